// Round 8
// baseline (9067.104 us; speedup 1.0000x reference)
//
#include <hip/hip_runtime.h>
#include <hip/hip_bf16.h>
#include <math.h>

// Problem constants
constexpr int kB = 4;
constexpr int kT = 1024;
constexpr int kC = 1024;
constexpr int kH = 16;
constexpr int kD = 64;
constexpr int kF = 4096;
constexpr int kBT = kB * kT;
constexpr int kSplit = 2;   // attention s-splits

typedef __attribute__((ext_vector_type(8))) short short8;   // bf16x8 MFMA frag (4 VGPRs)
typedef __attribute__((ext_vector_type(4))) float f32x4;    // MFMA acc frag

__device__ __forceinline__ unsigned short f2bf(float f) {
    __hip_bfloat16 h = __float2bfloat16(f);
    return __builtin_bit_cast(unsigned short, h);
}
__device__ __forceinline__ float bf2f(unsigned short u) {
    return __bfloat162float(__builtin_bit_cast(__hip_bfloat16, u));
}

// NOTE: __builtin_amdgcn_global_load_lds is BANNED in this harness — it
// deterministically killed the MI355X container (rounds 2-3 bisect).
// NOTE (r7): BK=32 LDS double-buffer REGRESSED (conflicts 2x, MfmaUtil 22->16);
// the binding constraint is exposed global-load latency, not barrier count.

// ---------------------------------------------------------------------------
// LayerNorm -> bf16 out. One block per row (C=1024), 256 threads.
// ---------------------------------------------------------------------------
__global__ __launch_bounds__(256) void ln_bf16_kernel(const float* __restrict__ x,
                                                      const float* __restrict__ g,
                                                      const float* __restrict__ bta,
                                                      unsigned short* __restrict__ out) {
    int row = blockIdx.x;
    int t = threadIdx.x;
    float4 xv = ((const float4*)(x + (size_t)row * kC))[t];
    float s  = xv.x + xv.y + xv.z + xv.w;
    float sq = xv.x * xv.x + xv.y * xv.y + xv.z * xv.z + xv.w * xv.w;
    #pragma unroll
    for (int off = 32; off; off >>= 1) {
        s  += __shfl_xor(s, off);
        sq += __shfl_xor(sq, off);
    }
    __shared__ float sb[8];
    int wid = t >> 6, lane = t & 63;
    if (lane == 0) { sb[wid] = s; sb[4 + wid] = sq; }
    __syncthreads();
    s  = sb[0] + sb[1] + sb[2] + sb[3];
    sq = sb[4] + sb[5] + sb[6] + sb[7];
    float mean = s * (1.0f / kC);
    float var  = sq * (1.0f / kC) - mean * mean;
    float rs = rsqrtf(var + 1e-5f);
    float4 gv = ((const float4*)g)[t];
    float4 bv = ((const float4*)bta)[t];
    ushort4 o;
    o.x = f2bf((xv.x - mean) * rs * gv.x + bv.x);
    o.y = f2bf((xv.y - mean) * rs * gv.y + bv.y);
    o.z = f2bf((xv.z - mean) * rs * gv.z + bv.z);
    o.w = f2bf((xv.w - mean) * rs * gv.w + bv.w);
    *(ushort4*)(out + (size_t)row * kC + t * 4) = o;
}

// ---------------------------------------------------------------------------
// Batched weight transpose: fp32 (R x C) tile -> bf16 (C x R). One launch for
// all six weights; blockIdx.x decodes weight + tile.
// ---------------------------------------------------------------------------
__device__ __forceinline__ void tile_tr(const float* __restrict__ src,
                                        unsigned short* __restrict__ dst,
                                        int R, int C, int r0, int c0,
                                        float (*tile)[65]) {
    int tid = threadIdx.x;
    int tr = tid >> 4, tc4 = (tid & 15) * 4;
    #pragma unroll
    for (int p = 0; p < 4; p++) {
        float4 v = *(const float4*)(src + (size_t)(r0 + tr + p * 16) * C + c0 + tc4);
        tile[tr + p * 16][tc4 + 0] = v.x;
        tile[tr + p * 16][tc4 + 1] = v.y;
        tile[tr + p * 16][tc4 + 2] = v.z;
        tile[tr + p * 16][tc4 + 3] = v.w;
    }
    __syncthreads();
    #pragma unroll
    for (int p = 0; p < 4; p++) {
        int c = tr + p * 16;
        ushort4 o;
        o.x = f2bf(tile[tc4 + 0][c]);
        o.y = f2bf(tile[tc4 + 1][c]);
        o.z = f2bf(tile[tc4 + 2][c]);
        o.w = f2bf(tile[tc4 + 3][c]);
        *(ushort4*)(dst + (size_t)(c0 + c) * R + r0 + tc4) = o;
    }
}

__global__ __launch_bounds__(256) void transpose_all(const float* __restrict__ Wq,
                                                     const float* __restrict__ Wk,
                                                     const float* __restrict__ Wv,
                                                     const float* __restrict__ Wo,
                                                     const float* __restrict__ W1,
                                                     const float* __restrict__ W2,
                                                     unsigned short* __restrict__ wqkvt,
                                                     unsigned short* __restrict__ wot,
                                                     unsigned short* __restrict__ w1t,
                                                     unsigned short* __restrict__ w2t) {
    __shared__ float tile[64][65];
    int id = blockIdx.x;
    if (id < 768) {               // Wq/Wk/Wv: per-head (1024 x 64) tiles
        int wsel = id >> 8, t = id & 255;
        int z = t >> 4, xq = t & 15;
        const float* s = (wsel == 0 ? Wq : wsel == 1 ? Wk : Wv) + (size_t)z * 65536;
        tile_tr(s, wqkvt + (size_t)wsel * 1048576 + (size_t)z * 65536,
                1024, 64, xq * 64, 0, tile);
    } else if (id < 1024) {       // Wo 1024x1024
        int t = id - 768;
        tile_tr(Wo, wot, 1024, 1024, (t & 15) * 64, (t >> 4) * 64, tile);
    } else if (id < 2048) {       // W1 1024x4096
        int t = id - 1024;
        tile_tr(W1, w1t, 1024, 4096, (t & 15) * 64, (t >> 4) * 64, tile);
    } else {                      // W2 4096x1024
        int t = id - 2048;
        tile_tr(W2, w2t, 4096, 1024, (t & 63) * 64, (t >> 6) * 64, tile);
    }
}

// ---------------------------------------------------------------------------
// Extract V from qkv buffer and transpose to (B,H,D,T) bf16. grid (T/64, B*H).
// ---------------------------------------------------------------------------
__global__ __launch_bounds__(256) void transpose_v_kernel(const unsigned short* __restrict__ qkv,
                                                          unsigned short* __restrict__ vt) {
    __shared__ unsigned short tile[64][68];
    int bh = blockIdx.y, b = bh >> 4, h = bh & 15;
    int t0 = blockIdx.x * 64;
    int tid = threadIdx.x;
    int tr = tid >> 4, tc4 = (tid & 15) * 4;
    #pragma unroll
    for (int p = 0; p < 4; p++) {
        int t = t0 + tr + p * 16;
        ushort4 v = *(const ushort4*)(qkv + ((size_t)(b * kT + t)) * 3072 + 2048 + h * 64 + tc4);
        *(ushort4*)&tile[tr + p * 16][tc4] = v;
    }
    __syncthreads();
    #pragma unroll
    for (int p = 0; p < 4; p++) {
        int d = tr + p * 16;
        ushort4 o;
        o.x = tile[tc4 + 0][d];
        o.y = tile[tc4 + 1][d];
        o.z = tile[tc4 + 2][d];
        o.w = tile[tc4 + 3][d];
        *(ushort4*)(vt + ((size_t)(bh * 64 + d)) * kT + t0 + tc4) = o;
    }
}

// ---------------------------------------------------------------------------
// Fused pad-scan + meanv: per (b,h) block computes npad/first-unpad + mean of
// V over padded t. grid (B*H), 256 threads. Writes fu[b] (h==0 blocks).
// ---------------------------------------------------------------------------
__global__ __launch_bounds__(256) void meanv_kernel(const unsigned short* __restrict__ vt,
                                                    const int* __restrict__ pad,
                                                    float* __restrict__ meanv,
                                                    int* __restrict__ fu) {
    int bh = blockIdx.x, b = bh >> 4;
    int tid = threadIdx.x;
    __shared__ char padc[kT];
    __shared__ int ri[256];
    __shared__ float rf[256];
    int4 pv = *(const int4*)(pad + b * kT + tid * 4);
    padc[tid * 4 + 0] = (char)pv.x;
    padc[tid * 4 + 1] = (char)pv.y;
    padc[tid * 4 + 2] = (char)pv.z;
    padc[tid * 4 + 3] = (char)pv.w;
    int cnt = pv.x + pv.y + pv.z + pv.w;
    int f = kT;
    if (!pv.w) f = tid * 4 + 3;
    if (!pv.z) f = tid * 4 + 2;
    if (!pv.y) f = tid * 4 + 1;
    if (!pv.x) f = tid * 4 + 0;
    ri[tid] = f;
    __syncthreads();
    for (int o = 128; o; o >>= 1) {
        if (tid < o) ri[tid] = min(ri[tid], ri[tid + o]);
        __syncthreads();
    }
    int fu_s = ri[0];
    __syncthreads();
    ri[tid] = cnt;
    __syncthreads();
    for (int o = 128; o; o >>= 1) {
        if (tid < o) ri[tid] += ri[tid + o];
        __syncthreads();
    }
    int np = ri[0];
    int d = tid >> 2, seg = tid & 3;
    const unsigned short* row = vt + ((size_t)bh * 64 + d) * kT + seg * 256;
    float s = 0.f;
    for (int t = 0; t < 256; ++t)
        if (padc[seg * 256 + t]) s += bf2f(row[t]);
    rf[tid] = s;
    __syncthreads();
    if (seg == 0) {
        float tot = rf[tid] + rf[tid + 1] + rf[tid + 2] + rf[tid + 3];
        meanv[bh * 64 + d] = np > 0 ? tot / (float)np : 0.f;
    }
    if (tid == 0 && (bh & 15) == 0) fu[b] = fu_s;
}

// ---------------------------------------------------------------------------
// Split-s MFMA flash attention (LDS-staged K/V, register prefetch).
// grid (T/64, B*H, kSplit). Writes unnormalized O (bf16) + (m,l).
// ---------------------------------------------------------------------------
__global__ __launch_bounds__(256) void attn_partial(const unsigned short* __restrict__ qkv,
                                                    const unsigned short* __restrict__ vt,
                                                    const int* __restrict__ pad,
                                                    unsigned short* __restrict__ Opart,
                                                    float* __restrict__ Mpart,
                                                    float* __restrict__ Lpart) {
    __shared__ __align__(16) unsigned short Ks[64][72];   // [s][d], +8 pad
    __shared__ __align__(16) unsigned short Vs[64][72];   // [d][s], +8 pad
    __shared__ __align__(16) unsigned short Ps[4][16][72];// per-wave P [q][s]
    const int tid = threadIdx.x;
    const int x = blockIdx.x, bh = blockIdx.y, j = blockIdx.z;
    const int b = bh >> 4, h = bh & 15;
    const int wv = tid >> 6, lane = tid & 63;
    const int lm = lane & 15, lk = lane >> 4;
    const int srow = tid >> 2, scol = (tid & 3) * 16;   // staging: row, col base

    const int qrow = x * 64 + wv * 16 + lm;
    const size_t qoff = ((size_t)(b * kT + qrow)) * 3072 + h * 64 + lk * 8;
    short8 bq0 = *(const short8*)(qkv + qoff);
    short8 bq1 = *(const short8*)(qkv + qoff + 32);

    const unsigned short* kbase = qkv + ((size_t)(b * kT + srow)) * 3072 + 1024 + h * 64 + scol;
    const unsigned short* vbase = vt + ((size_t)(bh * 64 + srow)) * kT + scol;

    f32x4 o[4];
    #pragma unroll
    for (int dt = 0; dt < 4; dt++) o[dt] = (f32x4){0.f, 0.f, 0.f, 0.f};
    float m_i = -__builtin_inff(), l_i = 0.f;

    short8 kp0 = *(const short8*)(kbase + (size_t)(j * 64) * 3072);
    short8 kp1 = *(const short8*)(kbase + (size_t)(j * 64) * 3072 + 8);
    short8 vp0 = *(const short8*)(vbase + j * 64);
    short8 vp1 = *(const short8*)(vbase + j * 64 + 8);

    for (int c = j; c <= x; c += kSplit) {
        const int s0 = c * 64;
        *(short8*)&Ks[srow][scol] = kp0;
        *(short8*)&Ks[srow][scol + 8] = kp1;
        *(short8*)&Vs[srow][scol] = vp0;
        *(short8*)&Vs[srow][scol + 8] = vp1;
        __syncthreads();
        if (c + kSplit <= x) {
            const int sn = (c + kSplit) * 64;
            kp0 = *(const short8*)(kbase + (size_t)sn * 3072);
            kp1 = *(const short8*)(kbase + (size_t)sn * 3072 + 8);
            vp0 = *(const short8*)(vbase + sn);
            vp1 = *(const short8*)(vbase + sn + 8);
        }
        float xs[16];
        #pragma unroll
        for (int g = 0; g < 4; g++) {
            short8 ka0 = *(const short8*)&Ks[g * 16 + lm][lk * 8];
            short8 ka1 = *(const short8*)&Ks[g * 16 + lm][32 + lk * 8];
            f32x4 sc = (f32x4){0.f, 0.f, 0.f, 0.f};
            sc = __builtin_amdgcn_mfma_f32_16x16x32_bf16(ka0, bq0, sc, 0, 0, 0);
            sc = __builtin_amdgcn_mfma_f32_16x16x32_bf16(ka1, bq1, sc, 0, 0, 0);
            int sbase = s0 + g * 16 + lk * 4;
            int4 pv = *(const int4*)(pad + b * kT + sbase);
            int pa[4] = {pv.x, pv.y, pv.z, pv.w};
            #pragma unroll
            for (int r = 0; r < 4; r++) {
                float v = sc[r] * 0.03125f;           // C^-0.5
                if (sbase + r > qrow) v = -__builtin_inff();
                if (pa[r]) v = -1e9f;                 // pad override last (reference order)
                xs[g * 4 + r] = v;
            }
        }
        float mt = xs[0];
        #pragma unroll
        for (int i = 1; i < 16; i++) mt = fmaxf(mt, xs[i]);
        mt = fmaxf(mt, __shfl_xor(mt, 16));
        mt = fmaxf(mt, __shfl_xor(mt, 32));
        float mn = fmaxf(m_i, mt);
        float alpha = __expf(m_i - mn);
        float p[16], rs = 0.f;
        #pragma unroll
        for (int i = 0; i < 16; i++) { p[i] = __expf(xs[i] - mn); rs += p[i]; }
        rs += __shfl_xor(rs, 16);
        rs += __shfl_xor(rs, 32);
        l_i = l_i * alpha + rs;
        m_i = mn;
        #pragma unroll
        for (int g = 0; g < 4; g++) {
            ushort4 u;
            u.x = f2bf(p[g * 4 + 0]); u.y = f2bf(p[g * 4 + 1]);
            u.z = f2bf(p[g * 4 + 2]); u.w = f2bf(p[g * 4 + 3]);
            *(ushort4*)&Ps[wv][lm][g * 16 + lk * 4] = u;
        }
        float ar0 = __shfl(alpha, lk * 4 + 0);
        float ar1 = __shfl(alpha, lk * 4 + 1);
        float ar2 = __shfl(alpha, lk * 4 + 2);
        float ar3 = __shfl(alpha, lk * 4 + 3);
        #pragma unroll
        for (int dt = 0; dt < 4; dt++) {
            o[dt][0] *= ar0; o[dt][1] *= ar1; o[dt][2] *= ar2; o[dt][3] *= ar3;
        }
        short8 ap0 = *(const short8*)&Ps[wv][lm][lk * 8];
        short8 ap1 = *(const short8*)&Ps[wv][lm][32 + lk * 8];
        #pragma unroll
        for (int dt = 0; dt < 4; dt++) {
            short8 bv0 = *(const short8*)&Vs[dt * 16 + lm][lk * 8];
            short8 bv1 = *(const short8*)&Vs[dt * 16 + lm][32 + lk * 8];
            o[dt] = __builtin_amdgcn_mfma_f32_16x16x32_bf16(ap0, bv0, o[dt], 0, 0, 0);
            o[dt] = __builtin_amdgcn_mfma_f32_16x16x32_bf16(ap1, bv1, o[dt], 0, 0, 0);
        }
        __syncthreads();
    }
    const size_t base = ((size_t)(bh * kSplit + j)) * kT;
    if (lk == 0) {
        Mpart[base + qrow] = m_i;
        Lpart[base + qrow] = l_i;
    }
    #pragma unroll
    for (int dt = 0; dt < 4; dt++)
        #pragma unroll
        for (int r = 0; r < 4; r++) {
            int q = x * 64 + wv * 16 + lk * 4 + r;
            Opart[(base + q) * kD + dt * 16 + lm] = f2bf(o[dt][r]);
        }
}

// ---------------------------------------------------------------------------
// Merge split partials -> attnb (B,T,C) bf16, with all-padded-visible fixup:
// rows q < fu[b] get meanv (uniform attention over all padded keys).
// grid (T/64, B*H), 256 thr.
// ---------------------------------------------------------------------------
__global__ __launch_bounds__(256) void attn_merge(const unsigned short* __restrict__ Opart,
                                                  const float* __restrict__ Mpart,
                                                  const float* __restrict__ Lpart,
                                                  const float* __restrict__ meanv,
                                                  const int* __restrict__ fu,
                                                  unsigned short* __restrict__ attnb) {
    const int xq = blockIdx.x, bh = blockIdx.y;
    const int b = bh >> 4, h = bh & 15;
    const int tid = threadIdx.x;
    const int qo = tid >> 4, d4 = (tid & 15) * 4;
    const int f = fu[b];
    #pragma unroll
    for (int pass = 0; pass < 4; pass++) {
        int q = xq * 64 + pass * 16 + qo;
        ushort4 r;
        if (q < f) {
            r.x = f2bf(meanv[bh * 64 + d4 + 0]);
            r.y = f2bf(meanv[bh * 64 + d4 + 1]);
            r.z = f2bf(meanv[bh * 64 + d4 + 2]);
            r.w = f2bf(meanv[bh * 64 + d4 + 3]);
        } else {
            float m[kSplit], l[kSplit];
            float mstar = -__builtin_inff();
            #pragma unroll
            for (int jj = 0; jj < kSplit; jj++) {
                size_t base = ((size_t)(bh * kSplit + jj)) * kT + q;
                m[jj] = Mpart[base];
                l[jj] = Lpart[base];
                if (l[jj] > 0.f) mstar = fmaxf(mstar, m[jj]);
            }
            float acc0 = 0.f, acc1 = 0.f, acc2 = 0.f, acc3 = 0.f, L = 0.f;
            #pragma unroll
            for (int jj = 0; jj < kSplit; jj++) {
                if (l[jj] > 0.f) {
                    float wgt = __expf(m[jj] - mstar);
                    L += wgt * l[jj];
                    ushort4 ov = *(const ushort4*)&Opart[(((size_t)(bh * kSplit + jj)) * kT + q) * kD + d4];
                    acc0 += wgt * bf2f(ov.x);
                    acc1 += wgt * bf2f(ov.y);
                    acc2 += wgt * bf2f(ov.z);
                    acc3 += wgt * bf2f(ov.w);
                }
            }
            float inv = 1.0f / L;
            r.x = f2bf(acc0 * inv); r.y = f2bf(acc1 * inv);
            r.z = f2bf(acc2 * inv); r.w = f2bf(acc3 * inv);
        }
        *(ushort4*)&attnb[((size_t)(b * kT + q)) * kC + h * 64 + d4] = r;
    }
}

// ---------------------------------------------------------------------------
// bf16 MFMA GEMM (round-6 structure + depth-2 register prefetch):
// C(MxN) = A(MxK) . Bt(NxK)^T, fp32 acc. BK=64, single LDS buffer (stride-72
// rows), 2 barriers/iter, 256 threads (4 waves, 2x2). Loads for chunk i+2 are
// issued after barrier-1 of iter i -> ~2 iterations in flight (covers L2 200
// cyc fully, most of HBM 900 cyc).
// ---------------------------------------------------------------------------
template<int TM, int TN>
__global__ __launch_bounds__(256) void gemm_bt(const unsigned short* __restrict__ A,
                                               const unsigned short* __restrict__ Bt,
                                               const float* __restrict__ bias,
                                               float* __restrict__ Cf,
                                               unsigned short* __restrict__ Cb,
                                               int N, int K, int relu) {
    constexpr int AI = TM / 32, BJ = TN / 32;
    constexpr int TPRA = 256 / TM, TPRB = 256 / TN;          // threads per row
    constexpr int ACH = 64 / TPRA / 8, BCH = 64 / TPRB / 8;  // short8 chunks/thread
    __shared__ __align__(16) unsigned short As[TM][72];
    __shared__ __align__(16) unsigned short Bs[TN][72];
    const int tid = threadIdx.x;
    const int wv = tid >> 6, lane = tid & 63;
    const int lm = lane & 15, lk = lane >> 4;
    const int arow = tid / TPRA, acb = (tid % TPRA) * (64 / TPRA);
    const int brow = tid / TPRB, bcb = (tid % TPRB) * (64 / TPRB);
    const int bm = blockIdx.y * TM, bn = blockIdx.x * TN;
    const int wm = (wv >> 1) * (TM / 2), wn = (wv & 1) * (TN / 2);
    f32x4 acc[AI][BJ];
    #pragma unroll
    for (int i = 0; i < AI; i++)
        #pragma unroll
        for (int j = 0; j < BJ; j++) acc[i][j] = (f32x4){0.f, 0.f, 0.f, 0.f};

    const unsigned short* Ap = A + (size_t)(bm + arow) * K + acb;
    const unsigned short* Bp = Bt + (size_t)(bn + brow) * K + bcb;
    // depth-2 prefetch: two register sets, chunk i in set i&1
    short8 rA[2][ACH], rB[2][BCH];
    #pragma unroll
    for (int i = 0; i < ACH; i++) rA[0][i] = *(const short8*)(Ap + i * 8);
    #pragma unroll
    for (int i = 0; i < BCH; i++) rB[0][i] = *(const short8*)(Bp + i * 8);
    if (K > 64) {
        #pragma unroll
        for (int i = 0; i < ACH; i++) rA[1][i] = *(const short8*)(Ap + 64 + i * 8);
        #pragma unroll
        for (int i = 0; i < BCH; i++) rB[1][i] = *(const short8*)(Bp + 64 + i * 8);
    }

    for (int k0 = 0; k0 < K; k0 += 64) {
        const int cur = (k0 >> 6) & 1;
        // commit chunk k0 (loaded 2 iterations ago) to LDS
        #pragma unroll
        for (int i = 0; i < ACH; i++)
            *(short8*)&As[arow][acb + i * 8] = rA[cur][i];
        #pragma unroll
        for (int i = 0; i < BCH; i++)
            *(short8*)&Bs[brow][bcb + i * 8] = rB[cur][i];
        __syncthreads();
        // issue loads for chunk k0+128 into the freed set
        if (k0 + 128 < K) {
            #pragma unroll
            for (int i = 0; i < ACH; i++) rA[cur][i] = *(const short8*)(Ap + k0 + 128 + i * 8);
            #pragma unroll
            for (int i = 0; i < BCH; i++) rB[cur][i] = *(const short8*)(Bp + k0 + 128 + i * 8);
        }
        #pragma unroll
        for (int kk = 0; kk < 2; kk++) {
            short8 a[AI], bfr[BJ];
            #pragma unroll
            for (int i = 0; i < AI; i++)
                a[i] = *(const short8*)&As[wm + i * 16 + lm][kk * 32 + lk * 8];
            #pragma unroll
            for (int j = 0; j < BJ; j++)
                bfr[j] = *(const short8*)&Bs[wn + j * 16 + lm][kk * 32 + lk * 8];
            #pragma unroll
            for (int i = 0; i < AI; i++)
                #pragma unroll
                for (int j = 0; j < BJ; j++)
                    acc[i][j] = __builtin_amdgcn_mfma_f32_16x16x32_bf16(a[i], bfr[j], acc[i][j], 0, 0, 0);
        }
        __syncthreads();
    }
    #pragma unroll
    for (int j = 0; j < BJ; j++) {
        int col = bn + wn + j * 16 + lm;
        float bj = bias ? bias[col] : 0.f;
        #pragma unroll
        for (int i = 0; i < AI; i++) {
            #pragma unroll
            for (int r = 0; r < 4; r++) {
                int row = bm + wm + i * 16 + lk * 4 + r;
                float v = acc[i][j][r] + bj;
                if (relu) v = fmaxf(v, 0.f);
                if (Cf) Cf[(size_t)row * N + col] = v;
                else    Cb[(size_t)row * N + col] = f2bf(v);
            }
        }
    }
}

// ---------------------------------------------------------------------------
extern "C" void kernel_launch(void* const* d_in, const int* in_sizes, int n_in,
                              void* d_out, int out_size, void* d_ws, size_t ws_size,
                              hipStream_t stream) {
    (void)in_sizes; (void)n_in; (void)out_size; (void)ws_size;
    const float* x    = (const float*)d_in[0];
    const int*   pad  = (const int*)d_in[1];
    const float* Wq   = (const float*)d_in[2];
    const float* Wk   = (const float*)d_in[3];
    const float* Wv   = (const float*)d_in[4];
    const float* Wo   = (const float*)d_in[5];
    const float* bo   = (const float*)d_in[6];
    const float* ln1g = (const float*)d_in[7];
    const float* ln1b = (const float*)d_in[8];
    const float* ln2g = (const float*)d_in[9];
    const float* ln2b = (const float*)d_in[10];
    const float* W1   = (const float*)d_in[11];
    const float* b1   = (const float*)d_in[12];
    const float* W2   = (const float*)d_in[13];
    const float* b2   = (const float*)d_in[14];
    float* out = (float*)d_out;
    char* w = (char*)d_ws;

    // Workspace map (92 MB; ws >= 96 MB proven in round 1):
    //  [0,24)  qkv bf16 -> dead after attn_partial; [0,16) reused as proj fp32
    //  [16,24) h2   [24,32) vt   [32,40) attnb
    //  [40,48) w1t  [48,56) w2t  [56,58) wot
    //  [58,59) meanv / fu
    //  [59,91) phase-multiplexed: {h [59,67) + wqkvt [67,73)} -> Opart (16MB) -> ffn1 (32MB)
    //  [91,91.5) Mpart  [91.5,92) Lpart
    constexpr size_t MB = 1024 * 1024;
    unsigned short* qkv   = (unsigned short*)(w + 0);
    float*          proj  = (float*)(w + 0);
    unsigned short* h2    = (unsigned short*)(w + 16 * MB);
    unsigned short* vt    = (unsigned short*)(w + 24 * MB);
    unsigned short* attnb = (unsigned short*)(w + 32 * MB);
    unsigned short* w1t   = (unsigned short*)(w + 40 * MB);
    unsigned short* w2t   = (unsigned short*)(w + 48 * MB);
    unsigned short* wot   = (unsigned short*)(w + 56 * MB);
    float*          meanv = (float*)(w + 58 * MB);
    int*            fu    = (int*)(w + 58 * MB + 65536);
    unsigned short* h     = (unsigned short*)(w + 59 * MB);
    unsigned short* wqkvt = (unsigned short*)(w + 67 * MB);
    unsigned short* Opart = (unsigned short*)(w + 59 * MB);  // 64bh*2sp*1024q*64d bf16 = 16 MB
    unsigned short* ffn1  = (unsigned short*)(w + 59 * MB);  // 32 MB, after Opart dead
    float*          Mpart = (float*)(w + 91 * MB);
    float*          Lpart = (float*)(w + 91 * MB + 512 * 1024);

    transpose_all<<<3072, 256, 0, stream>>>(Wq, Wk, Wv, Wo, W1, W2,
                                            wqkvt, wot, w1t, w2t);
    ln_bf16_kernel<<<kBT, 256, 0, stream>>>(x, ln1g, ln1b, h);
    gemm_bt<128, 128><<<dim3(24, 32), 256, 0, stream>>>(h, wqkvt, nullptr, nullptr, qkv,
                                                        3072, kC, 0);
    transpose_v_kernel<<<dim3(16, 64), 256, 0, stream>>>(qkv, vt);
    meanv_kernel<<<kB * kH, 256, 0, stream>>>(vt, pad, meanv, fu);
    attn_partial<<<dim3(16, 64, kSplit), 256, 0, stream>>>(qkv, vt, pad, Opart, Mpart, Lpart);
    attn_merge<<<dim3(16, 64), 256, 0, stream>>>(Opart, Mpart, Lpart, meanv, fu, attnb);
    gemm_bt<128, 64><<<dim3(16, 32), 256, 0, stream>>>(attnb, wot, bo, proj, nullptr,
                                                       kC, kC, 0);
    ln_bf16_kernel<<<kBT, 256, 0, stream>>>(proj, ln2g, ln2b, h2);
    gemm_bt<128, 128><<<dim3(32, 32), 256, 0, stream>>>(h2, w1t, b1, nullptr, ffn1,
                                                        kF, kC, 1);
    gemm_bt<128, 64><<<dim3(16, 32), 256, 0, stream>>>(ffn1, w2t, b2, out, nullptr,
                                                       kC, kF, 0);
}

// Round 9
// 400.580 us; speedup vs baseline: 22.6349x; 22.6349x over previous
//
#include <hip/hip_runtime.h>
#include <hip/hip_bf16.h>
#include <math.h>

// Problem constants
constexpr int kB = 4;
constexpr int kT = 1024;
constexpr int kC = 1024;
constexpr int kH = 16;
constexpr int kD = 64;
constexpr int kF = 4096;
constexpr int kBT = kB * kT;
constexpr int kSplit = 2;   // attention s-splits

typedef __attribute__((ext_vector_type(8))) short short8;   // bf16x8 MFMA frag (4 VGPRs)
typedef __attribute__((ext_vector_type(4))) float f32x4;    // MFMA acc frag

__device__ __forceinline__ unsigned short f2bf(float f) {
    __hip_bfloat16 h = __float2bfloat16(f);
    return __builtin_bit_cast(unsigned short, h);
}
__device__ __forceinline__ float bf2f(unsigned short u) {
    return __bfloat162float(__builtin_bit_cast(__hip_bfloat16, u));
}

// NOTE: __builtin_amdgcn_global_load_lds is BANNED in this harness — it
// deterministically killed the MI355X container (rounds 2-3 bisect).
// NOTE (r7): BK=32 LDS double-buffer REGRESSED (conflicts 2x, MfmaUtil 22->16).
// NOTE (r8): runtime-indexed prefetch arrays -> scratch spill -> 20x slower.
// Prefetch sets MUST be separate named arrays with static indexing.

// ---------------------------------------------------------------------------
// LayerNorm -> bf16 out. One block per row (C=1024), 256 threads.
// ---------------------------------------------------------------------------
__global__ __launch_bounds__(256) void ln_bf16_kernel(const float* __restrict__ x,
                                                      const float* __restrict__ g,
                                                      const float* __restrict__ bta,
                                                      unsigned short* __restrict__ out) {
    int row = blockIdx.x;
    int t = threadIdx.x;
    float4 xv = ((const float4*)(x + (size_t)row * kC))[t];
    float s  = xv.x + xv.y + xv.z + xv.w;
    float sq = xv.x * xv.x + xv.y * xv.y + xv.z * xv.z + xv.w * xv.w;
    #pragma unroll
    for (int off = 32; off; off >>= 1) {
        s  += __shfl_xor(s, off);
        sq += __shfl_xor(sq, off);
    }
    __shared__ float sb[8];
    int wid = t >> 6, lane = t & 63;
    if (lane == 0) { sb[wid] = s; sb[4 + wid] = sq; }
    __syncthreads();
    s  = sb[0] + sb[1] + sb[2] + sb[3];
    sq = sb[4] + sb[5] + sb[6] + sb[7];
    float mean = s * (1.0f / kC);
    float var  = sq * (1.0f / kC) - mean * mean;
    float rs = rsqrtf(var + 1e-5f);
    float4 gv = ((const float4*)g)[t];
    float4 bv = ((const float4*)bta)[t];
    ushort4 o;
    o.x = f2bf((xv.x - mean) * rs * gv.x + bv.x);
    o.y = f2bf((xv.y - mean) * rs * gv.y + bv.y);
    o.z = f2bf((xv.z - mean) * rs * gv.z + bv.z);
    o.w = f2bf((xv.w - mean) * rs * gv.w + bv.w);
    *(ushort4*)(out + (size_t)row * kC + t * 4) = o;
}

// ---------------------------------------------------------------------------
// Batched weight transpose: fp32 (R x C) tile -> bf16 (C x R). One launch for
// all six weights; blockIdx.x decodes weight + tile.
// ---------------------------------------------------------------------------
__device__ __forceinline__ void tile_tr(const float* __restrict__ src,
                                        unsigned short* __restrict__ dst,
                                        int R, int C, int r0, int c0,
                                        float (*tile)[65]) {
    int tid = threadIdx.x;
    int tr = tid >> 4, tc4 = (tid & 15) * 4;
    #pragma unroll
    for (int p = 0; p < 4; p++) {
        float4 v = *(const float4*)(src + (size_t)(r0 + tr + p * 16) * C + c0 + tc4);
        tile[tr + p * 16][tc4 + 0] = v.x;
        tile[tr + p * 16][tc4 + 1] = v.y;
        tile[tr + p * 16][tc4 + 2] = v.z;
        tile[tr + p * 16][tc4 + 3] = v.w;
    }
    __syncthreads();
    #pragma unroll
    for (int p = 0; p < 4; p++) {
        int c = tr + p * 16;
        ushort4 o;
        o.x = f2bf(tile[tc4 + 0][c]);
        o.y = f2bf(tile[tc4 + 1][c]);
        o.z = f2bf(tile[tc4 + 2][c]);
        o.w = f2bf(tile[tc4 + 3][c]);
        *(ushort4*)(dst + (size_t)(c0 + c) * R + r0 + tc4) = o;
    }
}

__global__ __launch_bounds__(256) void transpose_all(const float* __restrict__ Wq,
                                                     const float* __restrict__ Wk,
                                                     const float* __restrict__ Wv,
                                                     const float* __restrict__ Wo,
                                                     const float* __restrict__ W1,
                                                     const float* __restrict__ W2,
                                                     unsigned short* __restrict__ wqkvt,
                                                     unsigned short* __restrict__ wot,
                                                     unsigned short* __restrict__ w1t,
                                                     unsigned short* __restrict__ w2t) {
    __shared__ float tile[64][65];
    int id = blockIdx.x;
    if (id < 768) {               // Wq/Wk/Wv: per-head (1024 x 64) tiles
        int wsel = id >> 8, t = id & 255;
        int z = t >> 4, xq = t & 15;
        const float* s = (wsel == 0 ? Wq : wsel == 1 ? Wk : Wv) + (size_t)z * 65536;
        tile_tr(s, wqkvt + (size_t)wsel * 1048576 + (size_t)z * 65536,
                1024, 64, xq * 64, 0, tile);
    } else if (id < 1024) {       // Wo 1024x1024
        int t = id - 768;
        tile_tr(Wo, wot, 1024, 1024, (t & 15) * 64, (t >> 4) * 64, tile);
    } else if (id < 2048) {       // W1 1024x4096
        int t = id - 1024;
        tile_tr(W1, w1t, 1024, 4096, (t & 15) * 64, (t >> 4) * 64, tile);
    } else {                      // W2 4096x1024
        int t = id - 2048;
        tile_tr(W2, w2t, 4096, 1024, (t & 63) * 64, (t >> 6) * 64, tile);
    }
}

// ---------------------------------------------------------------------------
// Extract V from qkv buffer and transpose to (B,H,D,T) bf16. grid (T/64, B*H).
// ---------------------------------------------------------------------------
__global__ __launch_bounds__(256) void transpose_v_kernel(const unsigned short* __restrict__ qkv,
                                                          unsigned short* __restrict__ vt) {
    __shared__ unsigned short tile[64][68];
    int bh = blockIdx.y, b = bh >> 4, h = bh & 15;
    int t0 = blockIdx.x * 64;
    int tid = threadIdx.x;
    int tr = tid >> 4, tc4 = (tid & 15) * 4;
    #pragma unroll
    for (int p = 0; p < 4; p++) {
        int t = t0 + tr + p * 16;
        ushort4 v = *(const ushort4*)(qkv + ((size_t)(b * kT + t)) * 3072 + 2048 + h * 64 + tc4);
        *(ushort4*)&tile[tr + p * 16][tc4] = v;
    }
    __syncthreads();
    #pragma unroll
    for (int p = 0; p < 4; p++) {
        int d = tr + p * 16;
        ushort4 o;
        o.x = tile[tc4 + 0][d];
        o.y = tile[tc4 + 1][d];
        o.z = tile[tc4 + 2][d];
        o.w = tile[tc4 + 3][d];
        *(ushort4*)(vt + ((size_t)(bh * 64 + d)) * kT + t0 + tc4) = o;
    }
}

// ---------------------------------------------------------------------------
// Fused pad-scan + meanv: per (b,h) block computes npad/first-unpad + mean of
// V over padded t. grid (B*H), 256 threads. Writes fu[b] (h==0 blocks).
// ---------------------------------------------------------------------------
__global__ __launch_bounds__(256) void meanv_kernel(const unsigned short* __restrict__ vt,
                                                    const int* __restrict__ pad,
                                                    float* __restrict__ meanv,
                                                    int* __restrict__ fu) {
    int bh = blockIdx.x, b = bh >> 4;
    int tid = threadIdx.x;
    __shared__ char padc[kT];
    __shared__ int ri[256];
    __shared__ float rf[256];
    int4 pv = *(const int4*)(pad + b * kT + tid * 4);
    padc[tid * 4 + 0] = (char)pv.x;
    padc[tid * 4 + 1] = (char)pv.y;
    padc[tid * 4 + 2] = (char)pv.z;
    padc[tid * 4 + 3] = (char)pv.w;
    int cnt = pv.x + pv.y + pv.z + pv.w;
    int f = kT;
    if (!pv.w) f = tid * 4 + 3;
    if (!pv.z) f = tid * 4 + 2;
    if (!pv.y) f = tid * 4 + 1;
    if (!pv.x) f = tid * 4 + 0;
    ri[tid] = f;
    __syncthreads();
    for (int o = 128; o; o >>= 1) {
        if (tid < o) ri[tid] = min(ri[tid], ri[tid + o]);
        __syncthreads();
    }
    int fu_s = ri[0];
    __syncthreads();
    ri[tid] = cnt;
    __syncthreads();
    for (int o = 128; o; o >>= 1) {
        if (tid < o) ri[tid] += ri[tid + o];
        __syncthreads();
    }
    int np = ri[0];
    int d = tid >> 2, seg = tid & 3;
    const unsigned short* row = vt + ((size_t)bh * 64 + d) * kT + seg * 256;
    float s = 0.f;
    for (int t = 0; t < 256; ++t)
        if (padc[seg * 256 + t]) s += bf2f(row[t]);
    rf[tid] = s;
    __syncthreads();
    if (seg == 0) {
        float tot = rf[tid] + rf[tid + 1] + rf[tid + 2] + rf[tid + 3];
        meanv[bh * 64 + d] = np > 0 ? tot / (float)np : 0.f;
    }
    if (tid == 0 && (bh & 15) == 0) fu[b] = fu_s;
}

// ---------------------------------------------------------------------------
// Split-s MFMA flash attention (LDS-staged K/V, register prefetch).
// grid (T/64, B*H, kSplit). Writes unnormalized O (bf16) + (m,l).
// ---------------------------------------------------------------------------
__global__ __launch_bounds__(256) void attn_partial(const unsigned short* __restrict__ qkv,
                                                    const unsigned short* __restrict__ vt,
                                                    const int* __restrict__ pad,
                                                    unsigned short* __restrict__ Opart,
                                                    float* __restrict__ Mpart,
                                                    float* __restrict__ Lpart) {
    __shared__ __align__(16) unsigned short Ks[64][72];   // [s][d], +8 pad
    __shared__ __align__(16) unsigned short Vs[64][72];   // [d][s], +8 pad
    __shared__ __align__(16) unsigned short Ps[4][16][72];// per-wave P [q][s]
    const int tid = threadIdx.x;
    const int x = blockIdx.x, bh = blockIdx.y, j = blockIdx.z;
    const int b = bh >> 4, h = bh & 15;
    const int wv = tid >> 6, lane = tid & 63;
    const int lm = lane & 15, lk = lane >> 4;
    const int srow = tid >> 2, scol = (tid & 3) * 16;   // staging: row, col base

    const int qrow = x * 64 + wv * 16 + lm;
    const size_t qoff = ((size_t)(b * kT + qrow)) * 3072 + h * 64 + lk * 8;
    short8 bq0 = *(const short8*)(qkv + qoff);
    short8 bq1 = *(const short8*)(qkv + qoff + 32);

    const unsigned short* kbase = qkv + ((size_t)(b * kT + srow)) * 3072 + 1024 + h * 64 + scol;
    const unsigned short* vbase = vt + ((size_t)(bh * 64 + srow)) * kT + scol;

    f32x4 o[4];
    #pragma unroll
    for (int dt = 0; dt < 4; dt++) o[dt] = (f32x4){0.f, 0.f, 0.f, 0.f};
    float m_i = -__builtin_inff(), l_i = 0.f;

    short8 kp0 = *(const short8*)(kbase + (size_t)(j * 64) * 3072);
    short8 kp1 = *(const short8*)(kbase + (size_t)(j * 64) * 3072 + 8);
    short8 vp0 = *(const short8*)(vbase + j * 64);
    short8 vp1 = *(const short8*)(vbase + j * 64 + 8);

    for (int c = j; c <= x; c += kSplit) {
        const int s0 = c * 64;
        *(short8*)&Ks[srow][scol] = kp0;
        *(short8*)&Ks[srow][scol + 8] = kp1;
        *(short8*)&Vs[srow][scol] = vp0;
        *(short8*)&Vs[srow][scol + 8] = vp1;
        __syncthreads();
        if (c + kSplit <= x) {
            const int sn = (c + kSplit) * 64;
            kp0 = *(const short8*)(kbase + (size_t)sn * 3072);
            kp1 = *(const short8*)(kbase + (size_t)sn * 3072 + 8);
            vp0 = *(const short8*)(vbase + sn);
            vp1 = *(const short8*)(vbase + sn + 8);
        }
        float xs[16];
        #pragma unroll
        for (int g = 0; g < 4; g++) {
            short8 ka0 = *(const short8*)&Ks[g * 16 + lm][lk * 8];
            short8 ka1 = *(const short8*)&Ks[g * 16 + lm][32 + lk * 8];
            f32x4 sc = (f32x4){0.f, 0.f, 0.f, 0.f};
            sc = __builtin_amdgcn_mfma_f32_16x16x32_bf16(ka0, bq0, sc, 0, 0, 0);
            sc = __builtin_amdgcn_mfma_f32_16x16x32_bf16(ka1, bq1, sc, 0, 0, 0);
            int sbase = s0 + g * 16 + lk * 4;
            int4 pv = *(const int4*)(pad + b * kT + sbase);
            int pa[4] = {pv.x, pv.y, pv.z, pv.w};
            #pragma unroll
            for (int r = 0; r < 4; r++) {
                float v = sc[r] * 0.03125f;           // C^-0.5
                if (sbase + r > qrow) v = -__builtin_inff();
                if (pa[r]) v = -1e9f;                 // pad override last (reference order)
                xs[g * 4 + r] = v;
            }
        }
        float mt = xs[0];
        #pragma unroll
        for (int i = 1; i < 16; i++) mt = fmaxf(mt, xs[i]);
        mt = fmaxf(mt, __shfl_xor(mt, 16));
        mt = fmaxf(mt, __shfl_xor(mt, 32));
        float mn = fmaxf(m_i, mt);
        float alpha = __expf(m_i - mn);
        float p[16], rs = 0.f;
        #pragma unroll
        for (int i = 0; i < 16; i++) { p[i] = __expf(xs[i] - mn); rs += p[i]; }
        rs += __shfl_xor(rs, 16);
        rs += __shfl_xor(rs, 32);
        l_i = l_i * alpha + rs;
        m_i = mn;
        #pragma unroll
        for (int g = 0; g < 4; g++) {
            ushort4 u;
            u.x = f2bf(p[g * 4 + 0]); u.y = f2bf(p[g * 4 + 1]);
            u.z = f2bf(p[g * 4 + 2]); u.w = f2bf(p[g * 4 + 3]);
            *(ushort4*)&Ps[wv][lm][g * 16 + lk * 4] = u;
        }
        float ar0 = __shfl(alpha, lk * 4 + 0);
        float ar1 = __shfl(alpha, lk * 4 + 1);
        float ar2 = __shfl(alpha, lk * 4 + 2);
        float ar3 = __shfl(alpha, lk * 4 + 3);
        #pragma unroll
        for (int dt = 0; dt < 4; dt++) {
            o[dt][0] *= ar0; o[dt][1] *= ar1; o[dt][2] *= ar2; o[dt][3] *= ar3;
        }
        short8 ap0 = *(const short8*)&Ps[wv][lm][lk * 8];
        short8 ap1 = *(const short8*)&Ps[wv][lm][32 + lk * 8];
        #pragma unroll
        for (int dt = 0; dt < 4; dt++) {
            short8 bv0 = *(const short8*)&Vs[dt * 16 + lm][lk * 8];
            short8 bv1 = *(const short8*)&Vs[dt * 16 + lm][32 + lk * 8];
            o[dt] = __builtin_amdgcn_mfma_f32_16x16x32_bf16(ap0, bv0, o[dt], 0, 0, 0);
            o[dt] = __builtin_amdgcn_mfma_f32_16x16x32_bf16(ap1, bv1, o[dt], 0, 0, 0);
        }
        __syncthreads();
    }
    const size_t base = ((size_t)(bh * kSplit + j)) * kT;
    if (lk == 0) {
        Mpart[base + qrow] = m_i;
        Lpart[base + qrow] = l_i;
    }
    #pragma unroll
    for (int dt = 0; dt < 4; dt++)
        #pragma unroll
        for (int r = 0; r < 4; r++) {
            int q = x * 64 + wv * 16 + lk * 4 + r;
            Opart[(base + q) * kD + dt * 16 + lm] = f2bf(o[dt][r]);
        }
}

// ---------------------------------------------------------------------------
// Merge split partials -> attnb (B,T,C) bf16, with all-padded-visible fixup:
// rows q < fu[b] get meanv (uniform attention over all padded keys).
// grid (T/64, B*H), 256 thr.
// ---------------------------------------------------------------------------
__global__ __launch_bounds__(256) void attn_merge(const unsigned short* __restrict__ Opart,
                                                  const float* __restrict__ Mpart,
                                                  const float* __restrict__ Lpart,
                                                  const float* __restrict__ meanv,
                                                  const int* __restrict__ fu,
                                                  unsigned short* __restrict__ attnb) {
    const int xq = blockIdx.x, bh = blockIdx.y;
    const int b = bh >> 4, h = bh & 15;
    const int tid = threadIdx.x;
    const int qo = tid >> 4, d4 = (tid & 15) * 4;
    const int f = fu[b];
    #pragma unroll
    for (int pass = 0; pass < 4; pass++) {
        int q = xq * 64 + pass * 16 + qo;
        ushort4 r;
        if (q < f) {
            r.x = f2bf(meanv[bh * 64 + d4 + 0]);
            r.y = f2bf(meanv[bh * 64 + d4 + 1]);
            r.z = f2bf(meanv[bh * 64 + d4 + 2]);
            r.w = f2bf(meanv[bh * 64 + d4 + 3]);
        } else {
            float m[kSplit], l[kSplit];
            float mstar = -__builtin_inff();
            #pragma unroll
            for (int jj = 0; jj < kSplit; jj++) {
                size_t base = ((size_t)(bh * kSplit + jj)) * kT + q;
                m[jj] = Mpart[base];
                l[jj] = Lpart[base];
                if (l[jj] > 0.f) mstar = fmaxf(mstar, m[jj]);
            }
            float acc0 = 0.f, acc1 = 0.f, acc2 = 0.f, acc3 = 0.f, L = 0.f;
            #pragma unroll
            for (int jj = 0; jj < kSplit; jj++) {
                if (l[jj] > 0.f) {
                    float wgt = __expf(m[jj] - mstar);
                    L += wgt * l[jj];
                    ushort4 ov = *(const ushort4*)&Opart[(((size_t)(bh * kSplit + jj)) * kT + q) * kD + d4];
                    acc0 += wgt * bf2f(ov.x);
                    acc1 += wgt * bf2f(ov.y);
                    acc2 += wgt * bf2f(ov.z);
                    acc3 += wgt * bf2f(ov.w);
                }
            }
            float inv = 1.0f / L;
            r.x = f2bf(acc0 * inv); r.y = f2bf(acc1 * inv);
            r.z = f2bf(acc2 * inv); r.w = f2bf(acc3 * inv);
        }
        *(ushort4*)&attnb[((size_t)(b * kT + q)) * kC + h * 64 + d4] = r;
    }
}

// ---------------------------------------------------------------------------
// bf16 MFMA GEMM, depth-2 register prefetch with STATIC set indexing:
// C(MxN) = A(MxK) . Bt(NxK)^T, fp32 acc. BK=64, single LDS buffer (stride-72
// rows), K-loop advances 128/iter in two unrolled phases (set0/set1 are
// separate named arrays -> registers, r8 lesson). Loads for chunk i+2 issue
// right after barrier-1 of chunk i -> ~2 compute phases in flight.
// Requires K % 128 == 0 (K = 1024 or 4096 here).
// ---------------------------------------------------------------------------
template<int TM, int TN>
__global__ __launch_bounds__(256) void gemm_bt(const unsigned short* __restrict__ A,
                                               const unsigned short* __restrict__ Bt,
                                               const float* __restrict__ bias,
                                               float* __restrict__ Cf,
                                               unsigned short* __restrict__ Cb,
                                               int N, int K, int relu) {
    constexpr int AI = TM / 32, BJ = TN / 32;
    constexpr int TPRA = 256 / TM, TPRB = 256 / TN;          // threads per row
    constexpr int ACH = 64 / TPRA / 8, BCH = 64 / TPRB / 8;  // short8 chunks/thread
    __shared__ __align__(16) unsigned short As[TM][72];
    __shared__ __align__(16) unsigned short Bs[TN][72];
    const int tid = threadIdx.x;
    const int wv = tid >> 6, lane = tid & 63;
    const int lm = lane & 15, lk = lane >> 4;
    const int arow = tid / TPRA, acb = (tid % TPRA) * (64 / TPRA);
    const int brow = tid / TPRB, bcb = (tid % TPRB) * (64 / TPRB);
    const int bm = blockIdx.y * TM, bn = blockIdx.x * TN;
    const int wm = (wv >> 1) * (TM / 2), wn = (wv & 1) * (TN / 2);
    f32x4 acc[AI][BJ];
    #pragma unroll
    for (int i = 0; i < AI; i++)
        #pragma unroll
        for (int j = 0; j < BJ; j++) acc[i][j] = (f32x4){0.f, 0.f, 0.f, 0.f};

    const unsigned short* Ap = A + (size_t)(bm + arow) * K + acb;
    const unsigned short* Bp = Bt + (size_t)(bn + brow) * K + bcb;
    short8 rA0[ACH], rB0[BCH], rA1[ACH], rB1[BCH];
    #pragma unroll
    for (int i = 0; i < ACH; i++) rA0[i] = *(const short8*)(Ap + i * 8);
    #pragma unroll
    for (int i = 0; i < BCH; i++) rB0[i] = *(const short8*)(Bp + i * 8);
    #pragma unroll
    for (int i = 0; i < ACH; i++) rA1[i] = *(const short8*)(Ap + 64 + i * 8);
    #pragma unroll
    for (int i = 0; i < BCH; i++) rB1[i] = *(const short8*)(Bp + 64 + i * 8);

    for (int k0 = 0; k0 < K; k0 += 128) {
        // ---- phase 0: chunk k0 (set 0) ----
        #pragma unroll
        for (int i = 0; i < ACH; i++) *(short8*)&As[arow][acb + i * 8] = rA0[i];
        #pragma unroll
        for (int i = 0; i < BCH; i++) *(short8*)&Bs[brow][bcb + i * 8] = rB0[i];
        __syncthreads();
        if (k0 + 128 < K) {
            #pragma unroll
            for (int i = 0; i < ACH; i++) rA0[i] = *(const short8*)(Ap + k0 + 128 + i * 8);
            #pragma unroll
            for (int i = 0; i < BCH; i++) rB0[i] = *(const short8*)(Bp + k0 + 128 + i * 8);
        }
        #pragma unroll
        for (int kk = 0; kk < 2; kk++) {
            short8 a[AI], bfr[BJ];
            #pragma unroll
            for (int i = 0; i < AI; i++)
                a[i] = *(const short8*)&As[wm + i * 16 + lm][kk * 32 + lk * 8];
            #pragma unroll
            for (int j = 0; j < BJ; j++)
                bfr[j] = *(const short8*)&Bs[wn + j * 16 + lm][kk * 32 + lk * 8];
            #pragma unroll
            for (int i = 0; i < AI; i++)
                #pragma unroll
                for (int j = 0; j < BJ; j++)
                    acc[i][j] = __builtin_amdgcn_mfma_f32_16x16x32_bf16(a[i], bfr[j], acc[i][j], 0, 0, 0);
        }
        __syncthreads();
        // ---- phase 1: chunk k0+64 (set 1) ----
        #pragma unroll
        for (int i = 0; i < ACH; i++) *(short8*)&As[arow][acb + i * 8] = rA1[i];
        #pragma unroll
        for (int i = 0; i < BCH; i++) *(short8*)&Bs[brow][bcb + i * 8] = rB1[i];
        __syncthreads();
        if (k0 + 192 < K) {
            #pragma unroll
            for (int i = 0; i < ACH; i++) rA1[i] = *(const short8*)(Ap + k0 + 192 + i * 8);
            #pragma unroll
            for (int i = 0; i < BCH; i++) rB1[i] = *(const short8*)(Bp + k0 + 192 + i * 8);
        }
        #pragma unroll
        for (int kk = 0; kk < 2; kk++) {
            short8 a[AI], bfr[BJ];
            #pragma unroll
            for (int i = 0; i < AI; i++)
                a[i] = *(const short8*)&As[wm + i * 16 + lm][kk * 32 + lk * 8];
            #pragma unroll
            for (int j = 0; j < BJ; j++)
                bfr[j] = *(const short8*)&Bs[wn + j * 16 + lm][kk * 32 + lk * 8];
            #pragma unroll
            for (int i = 0; i < AI; i++)
                #pragma unroll
                for (int j = 0; j < BJ; j++)
                    acc[i][j] = __builtin_amdgcn_mfma_f32_16x16x32_bf16(a[i], bfr[j], acc[i][j], 0, 0, 0);
        }
        __syncthreads();
    }
    #pragma unroll
    for (int j = 0; j < BJ; j++) {
        int col = bn + wn + j * 16 + lm;
        float bj = bias ? bias[col] : 0.f;
        #pragma unroll
        for (int i = 0; i < AI; i++) {
            #pragma unroll
            for (int r = 0; r < 4; r++) {
                int row = bm + wm + i * 16 + lk * 4 + r;
                float v = acc[i][j][r] + bj;
                if (relu) v = fmaxf(v, 0.f);
                if (Cf) Cf[(size_t)row * N + col] = v;
                else    Cb[(size_t)row * N + col] = f2bf(v);
            }
        }
    }
}

// ---------------------------------------------------------------------------
extern "C" void kernel_launch(void* const* d_in, const int* in_sizes, int n_in,
                              void* d_out, int out_size, void* d_ws, size_t ws_size,
                              hipStream_t stream) {
    (void)in_sizes; (void)n_in; (void)out_size; (void)ws_size;
    const float* x    = (const float*)d_in[0];
    const int*   pad  = (const int*)d_in[1];
    const float* Wq   = (const float*)d_in[2];
    const float* Wk   = (const float*)d_in[3];
    const float* Wv   = (const float*)d_in[4];
    const float* Wo   = (const float*)d_in[5];
    const float* bo   = (const float*)d_in[6];
    const float* ln1g = (const float*)d_in[7];
    const float* ln1b = (const float*)d_in[8];
    const float* ln2g = (const float*)d_in[9];
    const float* ln2b = (const float*)d_in[10];
    const float* W1   = (const float*)d_in[11];
    const float* b1   = (const float*)d_in[12];
    const float* W2   = (const float*)d_in[13];
    const float* b2   = (const float*)d_in[14];
    float* out = (float*)d_out;
    char* w = (char*)d_ws;

    // Workspace map (92 MB; ws >= 96 MB proven in round 1):
    //  [0,24)  qkv bf16 -> dead after attn_partial; [0,16) reused as proj fp32
    //  [16,24) h2   [24,32) vt   [32,40) attnb
    //  [40,48) w1t  [48,56) w2t  [56,58) wot
    //  [58,59) meanv / fu
    //  [59,91) phase-multiplexed: {h [59,67) + wqkvt [67,73)} -> Opart (16MB) -> ffn1 (32MB)
    //  [91,91.5) Mpart  [91.5,92) Lpart
    constexpr size_t MB = 1024 * 1024;
    unsigned short* qkv   = (unsigned short*)(w + 0);
    float*          proj  = (float*)(w + 0);
    unsigned short* h2    = (unsigned short*)(w + 16 * MB);
    unsigned short* vt    = (unsigned short*)(w + 24 * MB);
    unsigned short* attnb = (unsigned short*)(w + 32 * MB);
    unsigned short* w1t   = (unsigned short*)(w + 40 * MB);
    unsigned short* w2t   = (unsigned short*)(w + 48 * MB);
    unsigned short* wot   = (unsigned short*)(w + 56 * MB);
    float*          meanv = (float*)(w + 58 * MB);
    int*            fu    = (int*)(w + 58 * MB + 65536);
    unsigned short* h     = (unsigned short*)(w + 59 * MB);
    unsigned short* wqkvt = (unsigned short*)(w + 67 * MB);
    unsigned short* Opart = (unsigned short*)(w + 59 * MB);  // 64bh*2sp*1024q*64d bf16 = 16 MB
    unsigned short* ffn1  = (unsigned short*)(w + 59 * MB);  // 32 MB, after Opart dead
    float*          Mpart = (float*)(w + 91 * MB);
    float*          Lpart = (float*)(w + 91 * MB + 512 * 1024);

    transpose_all<<<3072, 256, 0, stream>>>(Wq, Wk, Wv, Wo, W1, W2,
                                            wqkvt, wot, w1t, w2t);
    ln_bf16_kernel<<<kBT, 256, 0, stream>>>(x, ln1g, ln1b, h);
    gemm_bt<128, 128><<<dim3(24, 32), 256, 0, stream>>>(h, wqkvt, nullptr, nullptr, qkv,
                                                        3072, kC, 0);
    transpose_v_kernel<<<dim3(16, 64), 256, 0, stream>>>(qkv, vt);
    meanv_kernel<<<kB * kH, 256, 0, stream>>>(vt, pad, meanv, fu);
    attn_partial<<<dim3(16, 64, kSplit), 256, 0, stream>>>(qkv, vt, pad, Opart, Mpart, Lpart);
    attn_merge<<<dim3(16, 64), 256, 0, stream>>>(Opart, Mpart, Lpart, meanv, fu, attnb);
    gemm_bt<128, 64><<<dim3(16, 32), 256, 0, stream>>>(attnb, wot, bo, proj, nullptr,
                                                       kC, kC, 0);
    ln_bf16_kernel<<<kBT, 256, 0, stream>>>(proj, ln2g, ln2b, h2);
    gemm_bt<128, 128><<<dim3(32, 32), 256, 0, stream>>>(h2, w1t, b1, nullptr, ffn1,
                                                        kF, kC, 1);
    gemm_bt<128, 64><<<dim3(16, 32), 256, 0, stream>>>(ffn1, w2t, b2, out, nullptr,
                                                       kC, kF, 0);
}